// Round 1
// baseline (264.598 us; speedup 1.0000x reference)
//
#include <hip/hip_runtime.h>
#include <math.h>

#define NBINS 8
#define IMG 224
#define HC 28                 // cells per side
#define OUTPER (HC*HC*NBINS)  // 6272
#define BATCH 256
#define PL (IMG*IMG)          // floats per plane

// Gray loader: EDGE=true only for cell rows 0 and 27 (needs row clamp+zero);
// interior strips (26/28 of blocks) take the clamp-free path. Uniform branch.
template<bool EDGE>
__device__ __forceinline__ void load_gray(const float* __restrict__ xb,
    int r0, int c0, int cl, int lane, float v[10], float& hl, float& hr)
{
    #pragma unroll
    for (int j = 0; j < 10; ++j) {
        int gr  = r0 - 1 + j;
        int grc = EDGE ? (gr < 0 ? 0 : (gr > IMG - 1 ? IMG - 1 : gr)) : gr;
        const float* p = xb + grc * IMG + cl;
        float gv = 0.2989f * p[0] + 0.587f * p[PL] + 0.114f * p[2 * PL];
        v[j] = (EDGE && (gr < 0 || gr > IMG - 1)) ? 0.f : gv;
    }
    // halo grays: lanes 54..63 hold left col (c0-1) rows 0..9,
    // lanes 44..53 hold right col (c0+64) rows 0..9 (others garbage)
    {
        int jl = lane - 54; jl = jl < 0 ? 0 : (jl > 9 ? 9 : jl);
        int gr = r0 - 1 + jl;
        int grc = EDGE ? (gr < 0 ? 0 : (gr > IMG - 1 ? IMG - 1 : gr)) : gr;
        int colL = c0 - 1; bool zc = colL < 0; int colc = zc ? 0 : colL;
        const float* p = xb + grc * IMG + colc;
        float gv = 0.2989f * p[0] + 0.587f * p[PL] + 0.114f * p[2 * PL];
        hl = (zc || (EDGE && (gr < 0 || gr > IMG - 1))) ? 0.f : gv;
    }
    {
        int jr = lane - 44; jr = jr < 0 ? 0 : (jr > 9 ? 9 : jr);
        int gr = r0 - 1 + jr;
        int grc = EDGE ? (gr < 0 ? 0 : (gr > IMG - 1 ? IMG - 1 : gr)) : gr;
        int colR = c0 + 64; bool zc = colR > IMG - 1; int colc = zc ? IMG - 1 : colR;
        const float* p = xb + grc * IMG + colc;
        float gv = 0.2989f * p[0] + 0.587f * p[PL] + 0.114f * p[2 * PL];
        hr = (zc || (EDGE && (gr < 0 || gr > IMG - 1))) ? 0.f : gv;
    }
}

// ---------------- main kernel: one WAVE per (image, cell-row, 64-col slab) -
// grid 7168 x 256. ZERO barriers: each wave owns hist[wv][*] (wave-private
// LDS row), so the 8-bin histogram goes through ds_add_f32 atomics instead
// of the old 192-VALU cndmask accumulate + 24-shuffle butterfly. gauss is
// separable exp(-(i-3.5)^2/2) products -> computed in-register (no loads,
// -16 VGPR from dropping wgt[8]/h[8]).
__global__ __launch_bounds__(256) void hog_main_kernel(
    const float* __restrict__ x, const float* __restrict__ gauss,
    float* __restrict__ out, float* __restrict__ partial)
{
    __shared__ float hist[4][64];    // [wave][cell*8+bin], wave-private rows

    const int tid  = threadIdx.x;
    const int wv   = tid >> 6;
    const int lane = tid & 63;
    const int bc   = blockIdx.x;          // 0..7167
    const int b    = bc / HC;
    const int cr   = bc - b * HC;         // cell row 0..27
    const int r0   = cr * 8;
    const int c0   = wv * 64;
    const int c    = c0 + lane;           // output column; live if < IMG
    const int cl   = c > IMG - 1 ? IMG - 1 : c;

    const float* xb = x + (size_t)b * 3 * PL;

    hist[wv][lane] = 0.f;                 // wave-private init, no barrier

    float v[10], hl, hr;
    if (cr == 0 || cr == HC - 1) load_gray<true >(xb, r0, c0, cl, lane, v, hl, hr);
    else                         load_gray<false>(xb, r0, c0, cl, lane, v, hl, hr);

    // gauss weight: gauss[sr*8+wc] = e(sr)*e(wc), e(i)=exp(-(i-3.5)^2/2).
    // e(wc) via one v_exp_f32; e(sr) folded as literals per unrolled row.
    const int wc = lane & 7;
    float tt = (float)wc - 3.5f;
    float gw = __builtin_amdgcn_exp2f(-(tt * tt) * 0.72134752f); // log2(e)/2
    const float EROW[8] = { 0.0021874911f, 0.043936934f, 0.32465247f, 0.88249690f,
                            0.88249690f, 0.32465247f, 0.043936934f, 0.0021874911f };

    float* cellp = &hist[wv][(lane >> 3) << 3];   // this lane's cell base

    // left/right neighbor of row j, with slab-edge + image-edge fixes
    auto mklr = [&](int j, float& lf, float& rt) {
        float a = __shfl_up(v[j], 1, 64);
        float hLj = __shfl(hl, 54 + j, 64);
        lf = (lane == 0) ? hLj : a;
        float d = __shfl_down(v[j], 1, 64);
        float hRj = __shfl(hr, 44 + j, 64);
        d = (lane == 63) ? hRj : d;
        rt = (c >= IMG - 1) ? 0.f : d;            // col 224 is zero-pad
    };

    float tL, tC, tR, mL, mC, mR;
    mklr(0, tL, tR); tC = v[0];
    mklr(1, mL, mR); mC = v[1];

    #pragma unroll
    for (int sr = 0; sr < 8; ++sr) {
        float bL, bR, bC = v[sr + 2];
        mklr(sr + 2, bL, bR);

        float gx = (tR - tL) + 2.f * (mR - mL) + (bR - bL);
        float gy = (bL - tL) + 2.f * (bC - tC) + (bR - tR);
        float mag = __builtin_amdgcn_sqrtf(gx * gx + gy * gy + 1e-6f);
        float ax = fabsf(gx), ay = fabsf(gy);

        // exact-octant bin == floor(mod(atan2(gy,gx),2pi)/(pi/4));
        // boundary semantics verified in prior rounds — do not touch
        int bin;
        if (gy > 0.f)       bin = (gx > 0.f)  ? ((gy < gx) ? 0 : 1)
                                : (gx == 0.f) ? 2 : ((ay > ax) ? 2 : 3);
        else if (gy == 0.f) bin = (gx < 0.f) ? 4 : 0;
        else                bin = (gx < 0.f)  ? ((ay < ax) ? 4 : 5)
                                : (gx == 0.f) ? 6 : ((ay > ax) ? 6 : 7);

        float wm = EROW[sr] * (gw * mag);
        atomicAdd(cellp + bin, wm);      // ds_add_f32, wave-private region

        tL = mL; tC = mC; tR = mR;
        mL = bL; mC = bC; mR = bR;
    }

    // drain this wave's LDS atomics (in-order LDS pipe; fence for compiler+HW)
    asm volatile("s_waitcnt lgkmcnt(0)" ::: "memory");
    float val = hist[wv][lane];          // lane == cell*8 + wc exactly

    float ssq = 0.f;
    if (c < IMG) {
        out[(size_t)b * OUTPER + (size_t)cr * IMG + c] = val;  // coalesced
        ssq = val * val;
    }

    // per-(strip,slab) sumsq partial: wave reduce, lane 0 writes
    #pragma unroll
    for (int o = 32; o > 0; o >>= 1) ssq += __shfl_down(ssq, o, 64);
    if (lane == 0) partial[bc * 4 + wv] = ssq;   // [b][cr][slab] contiguous
}

// ---------------- norm kernel: FOUR blocks (256 thr) per image -------------
// old version ran 256 blocks = 1 wave/SIMD = pure latency. Each block now
// redundantly reduces the 112 L2-hot partials (cheap) and scales a quarter.
__global__ __launch_bounds__(256) void hog_norm_kernel(
    float* __restrict__ out, const float* __restrict__ partial)
{
    const int bq = blockIdx.x, tid = threadIdx.x;
    const int b = bq >> 2, q = bq & 3;
    __shared__ float wsum[4];
    __shared__ float s_inv;
    float s = (tid < HC * 4) ? partial[b * HC * 4 + tid] : 0.f;
    #pragma unroll
    for (int o = 32; o > 0; o >>= 1) s += __shfl_down(s, o, 64);
    if ((tid & 63) == 0) wsum[tid >> 6] = s;
    __syncthreads();
    if (tid == 0) {
        float t = wsum[0] + wsum[1] + wsum[2] + wsum[3];
        s_inv = 1.0f / (sqrtf(t) + 1e-6f);
    }
    __syncthreads();
    float inv = s_inv;
    float4* o4 = (float4*)(out + (size_t)b * OUTPER + (size_t)q * (OUTPER / 4));
    for (int i = tid; i < OUTPER / 16; i += 256) {   // 392 float4 per quarter
        float4 w = o4[i];
        w.x *= inv; w.y *= inv; w.z *= inv; w.w *= inv;
        o4[i] = w;
    }
}

extern "C" void kernel_launch(void* const* d_in, const int* in_sizes, int n_in,
                              void* d_out, int out_size, void* d_ws, size_t ws_size,
                              hipStream_t stream) {
    const float* x     = (const float*)d_in[0];
    const float* gauss = (const float*)d_in[1];   // unused: separable constants inlined
    // d_in[2]=kx, d_in[3]=ky: compile-time Sobel constants (hardcoded)
    float* out     = (float*)d_out;
    float* partial = (float*)d_ws;       // 28672 floats, fully overwritten

    hog_main_kernel<<<BATCH * HC, 256, 0, stream>>>(x, gauss, out, partial);
    hog_norm_kernel<<<BATCH * 4, 256, 0, stream>>>(out, partial);
}

// Round 2
// 230.789 us; speedup vs baseline: 1.1465x; 1.1465x over previous
//
#include <hip/hip_runtime.h>
#include <math.h>

#define NBINS 8
#define IMG 224
#define HC 28                 // cells per side
#define OUTPER (HC*HC*NBINS)  // 6272
#define BATCH 256
#define PL (IMG*IMG)          // floats per plane

// pair-swap within quads (lane 2j <-> 2j+1): quad_perm(1,0,3,2) = 0xB1.
// Pure VALU (DPP), no DS-pipe traffic.
__device__ __forceinline__ float dpp_swap1(float x) {
    return __int_as_float(__builtin_amdgcn_update_dpp(
        0, __float_as_int(x), 0xB1, 0xF, 0xF, false));
}

// ---- gray loader: lane owns cols 4i..4i+3 of rows r0-1..r0+8 (float4) ----
// EDGE=true only for cr==0 / cr==27 (row clamp + zero). Lanes >=56 are
// zeroed so that shfl_down across the lane-55/56 boundary yields the
// col-224 zero-pad for free.
template<bool EDGE>
__device__ __forceinline__ void load_gray(const float* __restrict__ xb,
                                          int r0, int col4, int lane,
                                          float4 v[10])
{
    #pragma unroll
    for (int j = 0; j < 10; ++j) {
        int gr  = r0 - 1 + j;
        int grc = EDGE ? (gr < 0 ? 0 : (gr > IMG - 1 ? IMG - 1 : gr)) : gr;
        const float* p = xb + grc * IMG + col4;
        float4 R = *(const float4*)(p);
        float4 G = *(const float4*)(p + PL);
        float4 B = *(const float4*)(p + 2 * PL);
        float4 g;
        g.x = 0.2989f * R.x + 0.587f * G.x + 0.114f * B.x;
        g.y = 0.2989f * R.y + 0.587f * G.y + 0.114f * B.y;
        g.z = 0.2989f * R.z + 0.587f * G.z + 0.114f * B.z;
        g.w = 0.2989f * R.w + 0.587f * G.w + 0.114f * B.w;
        bool z = (lane >= 56) || (EDGE && (gr < 0 || gr > IMG - 1));
        if (z) { g.x = 0.f; g.y = 0.f; g.z = 0.f; g.w = 0.f; }
        v[j] = g;
    }
}

// ---------------- main kernel: ONE WAVE per (image, cell-row) -------------
// grid 1792 x 256: block = 4 waves = 4 consecutive cell-rows of one image.
// Lane i (0..55) owns output cols 4i..4i+3 via float4 loads: 30 wave-loads
// of 896B each (deep MLP), separable Sobel keeps neighbors in-register;
// only 4 shfl per output row cross lanes. Histogram in registers (VALU),
// cell = exactly 2 lanes -> one DPP pair-reduce, one float4 store per lane.
__global__ __launch_bounds__(256) void hog_main_kernel(
    const float* __restrict__ x, const float* __restrict__ gauss,
    float* __restrict__ out, float* __restrict__ partial)
{
    const int tid  = threadIdx.x;
    const int wv   = tid >> 6;
    const int lane = tid & 63;
    const int bc   = blockIdx.x;            // 0..1791
    const int b    = bc / 7;
    const int cr   = (bc - b * 7) * 4 + wv; // cell row 0..27 (per wave)
    const int r0   = cr * 8;
    const int li   = lane < 55 ? lane : 55; // clamp dead lanes
    const int col4 = li * 4;

    const float* xb = x + (size_t)b * 3 * PL;

    float4 v[10];
    if (cr == 0 || cr == HC - 1) load_gray<true >(xb, r0, col4, lane, v);
    else                         load_gray<false>(xb, r0, col4, lane, v);

    // separable gauss: w(sr, col) = EROW[sr] * ECOL[col&7]; ECOL symmetric,
    // so odd lanes (cols 4..7 of cell) use the reverse of even lanes (0..3)
    const float E0 = 0.0021874911f, E1 = 0.043936934f,
                E2 = 0.32465247f,   E3 = 0.88249690f;
    const bool odd = (lane & 1);
    const float ew0 = odd ? E3 : E0, ew1 = odd ? E2 : E1,
                ew2 = odd ? E1 : E2, ew3 = odd ? E0 : E3;
    const float EROW[8] = { E0, E1, E2, E3, E3, E2, E1, E0 };

    float h[8];
    #pragma unroll
    for (int k = 0; k < 8; ++k) h[k] = 0.f;

    auto pix = [&](float gx, float gy, float w) {
        float mag = __builtin_amdgcn_sqrtf(gx * gx + gy * gy + 1e-6f);
        float ax = fabsf(gx), ay = fabsf(gy);
        // exact-octant bin == floor(mod(atan2(gy,gx),2pi)/(pi/4));
        // boundary semantics verified in prior rounds — do not touch
        int bin;
        if (gy > 0.f)       bin = (gx > 0.f)  ? ((gy < gx) ? 0 : 1)
                                : (gx == 0.f) ? 2 : ((ay > ax) ? 2 : 3);
        else if (gy == 0.f) bin = (gx < 0.f) ? 4 : 0;
        else                bin = (gx < 0.f)  ? ((ay < ax) ? 4 : 5)
                                : (gx == 0.f) ? 6 : ((ay > ax) ? 6 : 7);
        float wm = w * mag;
        #pragma unroll
        for (int k = 0; k < 8; ++k) h[k] += (bin == k) ? wm : 0.f;
    };

    #pragma unroll
    for (int sr = 0; sr < 8; ++sr) {
        float4 t = v[sr], m = v[sr + 1], bt = v[sr + 2];
        float4 s, d;                       // vertical smooth / diff
        s.x = t.x + 2.f * m.x + bt.x;  s.y = t.y + 2.f * m.y + bt.y;
        s.z = t.z + 2.f * m.z + bt.z;  s.w = t.w + 2.f * m.w + bt.w;
        d.x = bt.x - t.x;  d.y = bt.y - t.y;
        d.z = bt.z - t.z;  d.w = bt.w - t.w;

        // lane-boundary neighbors (only 4 DS ops per row)
        float sL = __shfl_up(s.w, 1, 64);   sL = (lane == 0) ? 0.f : sL;
        float dL = __shfl_up(d.w, 1, 64);   dL = (lane == 0) ? 0.f : dL;
        float sR = __shfl_down(s.x, 1, 64); // lane55 <- lane56 == 0 (col224 pad)
        float dR = __shfl_down(d.x, 1, 64);

        float gx0 = s.y - sL,  gx1 = s.z - s.x,
              gx2 = s.w - s.y, gx3 = sR  - s.z;
        float gy0 = dL  + 2.f * d.x + d.y, gy1 = d.x + 2.f * d.y + d.z,
              gy2 = d.y + 2.f * d.z + d.w, gy3 = d.z + 2.f * d.w + dR;

        float er = EROW[sr];
        pix(gx0, gy0, er * ew0);
        pix(gx1, gy1, er * ew1);
        pix(gx2, gy2, er * ew2);
        pix(gx3, gy3, er * ew3);
    }

    // cell = lanes (2j, 2j+1): pair-reduce via DPP (VALU, no DS pipe)
    #pragma unroll
    for (int k = 0; k < 8; ++k) h[k] += dpp_swap1(h[k]);

    float ssq = 0.f;
    if (lane < 56) {
        float4 st = odd ? make_float4(h[4], h[5], h[6], h[7])
                        : make_float4(h[0], h[1], h[2], h[3]);
        *(float4*)(out + (size_t)b * OUTPER + (size_t)cr * IMG + 4 * lane) = st;
        ssq = st.x * st.x + st.y * st.y + st.z * st.z + st.w * st.w;
    }

    // per-(image, cell-row) sumsq partial
    #pragma unroll
    for (int o = 32; o > 0; o >>= 1) ssq += __shfl_down(ssq, o, 64);
    if (lane == 0) partial[b * HC + cr] = ssq;
}

// ---------------- norm kernel: FOUR blocks (256 thr) per image -------------
__global__ __launch_bounds__(256) void hog_norm_kernel(
    float* __restrict__ out, const float* __restrict__ partial)
{
    const int bq = blockIdx.x, tid = threadIdx.x;
    const int b = bq >> 2, q = bq & 3;
    __shared__ float wsum[4];
    __shared__ float s_inv;
    float s = (tid < HC) ? partial[b * HC + tid] : 0.f;   // lanes 0..27, wave 0
    #pragma unroll
    for (int o = 32; o > 0; o >>= 1) s += __shfl_down(s, o, 64);
    if ((tid & 63) == 0) wsum[tid >> 6] = s;
    __syncthreads();
    if (tid == 0) {
        float t = wsum[0] + wsum[1] + wsum[2] + wsum[3];
        s_inv = 1.0f / (sqrtf(t) + 1e-6f);
    }
    __syncthreads();
    float inv = s_inv;
    float4* o4 = (float4*)(out + (size_t)b * OUTPER + (size_t)q * (OUTPER / 4));
    for (int i = tid; i < OUTPER / 16; i += 256) {   // 392 float4 per quarter
        float4 w = o4[i];
        w.x *= inv; w.y *= inv; w.z *= inv; w.w *= inv;
        o4[i] = w;
    }
}

extern "C" void kernel_launch(void* const* d_in, const int* in_sizes, int n_in,
                              void* d_out, int out_size, void* d_ws, size_t ws_size,
                              hipStream_t stream) {
    const float* x     = (const float*)d_in[0];
    const float* gauss = (const float*)d_in[1];   // unused: separable constants inlined
    // d_in[2]=kx, d_in[3]=ky: compile-time Sobel constants (hardcoded)
    float* out     = (float*)d_out;
    float* partial = (float*)d_ws;       // 7168 floats, fully overwritten

    hog_main_kernel<<<BATCH * 7, 256, 0, stream>>>(x, gauss, out, partial);
    hog_norm_kernel<<<BATCH * 4, 256, 0, stream>>>(out, partial);
}